// Round 1
// baseline (2879.523 us; speedup 1.0000x reference)
//
#include <hip/hip_runtime.h>

#define N_NODES 50000
#define N_EDGES 1600000
#define FX 128
#define FE 8
#define FIN 136          // FX + FE
#define NPAD 50048       // pad rows so 64-row GEMM tiles can over-read safely

// ---------------------------------------------------------------- CSR build
__global__ void hist_kernel(const int* __restrict__ ei, int* __restrict__ deg) {
    int e = blockIdx.x * 256 + threadIdx.x;
    if (e >= N_EDGES) return;
    atomicAdd(&deg[ei[N_EDGES + e]], 1);
}

__global__ void scan_kernel(const int* __restrict__ deg, int* __restrict__ row_ptr,
                            int* __restrict__ cursor) {
    __shared__ int sums[1024];
    const int n = N_NODES;
    int t = threadIdx.x;
    int chunk = (n + 1023) >> 10;                    // 49
    int i0 = t * chunk;
    int i1 = i0 + chunk; if (i1 > n) i1 = n;
    int s = 0;
    for (int i = i0; i < i1; ++i) s += deg[i];
    sums[t] = s;
    __syncthreads();
    // Hillis-Steele inclusive scan over 1024 partials
    for (int off = 1; off < 1024; off <<= 1) {
        int v = (t >= off) ? sums[t - off] : 0;
        __syncthreads();
        sums[t] += v;
        __syncthreads();
    }
    int running = sums[t] - s;                       // exclusive prefix for this chunk
    for (int i = i0; i < i1; ++i) {
        row_ptr[i] = running;
        cursor[i]  = running;
        running += deg[i];
    }
    if (t == 1023) row_ptr[n] = sums[1023];
}

__global__ void fill_kernel(const int* __restrict__ ei, int* __restrict__ cursor,
                            int* __restrict__ csr_src) {
    int e = blockIdx.x * 256 + threadIdx.x;
    if (e >= N_EDGES) return;
    int src = ei[e];
    int dst = ei[N_EDGES + e];
    int pos = atomicAdd(&cursor[dst], 1);
    csr_src[pos] = src;
}

// ------------------------------------------------- edge-attr aggregation (once per branch)
__global__ void zero_ecols_kernel(float* __restrict__ agg) {
    int i = blockIdx.x * 256 + threadIdx.x;          // over N_NODES*FE
    if (i >= N_NODES * FE) return;
    agg[(size_t)(i >> 3) * FIN + FX + (i & 7)] = 0.f;
}

__global__ void scatter_e_kernel(const float* __restrict__ ea, const int* __restrict__ ei,
                                 float* __restrict__ agg) {
    int e = blockIdx.x * 256 + threadIdx.x;
    if (e >= N_EDGES) return;
    int dst = ei[N_EDGES + e];
    const float4 v0 = *reinterpret_cast<const float4*>(ea + (size_t)e * FE);
    const float4 v1 = *reinterpret_cast<const float4*>(ea + (size_t)e * FE + 4);
    float* p = agg + (size_t)dst * FIN + FX;
    atomicAdd(p + 0, v0.x); atomicAdd(p + 1, v0.y);
    atomicAdd(p + 2, v0.z); atomicAdd(p + 3, v0.w);
    atomicAdd(p + 4, v1.x); atomicAdd(p + 5, v1.y);
    atomicAdd(p + 6, v1.z); atomicAdd(p + 7, v1.w);
}

// ------------------------------------------------- sparse gather: agg_x[dst] = sum x[src]
// one 32-thread group per node, float4 per thread (32*4 = 128 features)
__global__ void gather_kernel(const float* __restrict__ x, const int* __restrict__ row_ptr,
                              const int* __restrict__ csr_src, float* __restrict__ agg) {
    int node = blockIdx.x * 8 + (threadIdx.x >> 5);
    if (node >= N_NODES) return;
    int lane = threadIdx.x & 31;
    int start = row_ptr[node], end = row_ptr[node + 1];
    float4 acc = {0.f, 0.f, 0.f, 0.f};
    int e = start;
    for (; e + 4 <= end; e += 4) {
        int s0 = csr_src[e], s1 = csr_src[e + 1], s2 = csr_src[e + 2], s3 = csr_src[e + 3];
        float4 v0 = *reinterpret_cast<const float4*>(&x[(size_t)s0 * FX + lane * 4]);
        float4 v1 = *reinterpret_cast<const float4*>(&x[(size_t)s1 * FX + lane * 4]);
        float4 v2 = *reinterpret_cast<const float4*>(&x[(size_t)s2 * FX + lane * 4]);
        float4 v3 = *reinterpret_cast<const float4*>(&x[(size_t)s3 * FX + lane * 4]);
        acc.x += v0.x + v1.x + v2.x + v3.x;
        acc.y += v0.y + v1.y + v2.y + v3.y;
        acc.z += v0.z + v1.z + v2.z + v3.z;
        acc.w += v0.w + v1.w + v2.w + v3.w;
    }
    for (; e < end; ++e) {
        int s = csr_src[e];
        float4 v = *reinterpret_cast<const float4*>(&x[(size_t)s * FX + lane * 4]);
        acc.x += v.x; acc.y += v.y; acc.z += v.z; acc.w += v.w;
    }
    *reinterpret_cast<float4*>(&agg[(size_t)node * FIN + lane * 4]) = acc;
}

// ------------------------------------------------- dense GEMM: out[N,128] = A[N,K] @ W[128,K]^T + b
// 64-row tile per block, 256 threads, 4x8 register tile per thread.
template <int K, int KP, bool LEAKY>
__global__ void gemm_kernel(const float* __restrict__ A, const float* __restrict__ W,
                            const float* __restrict__ bias, float* __restrict__ out) {
    __shared__ float As[64 * KP];
    const int row0 = blockIdx.x * 64;
    // cooperative load A tile (rows padded in ws, so no read guard needed)
    const float* Ab = A + (size_t)row0 * K;
    for (int idx = threadIdx.x * 4; idx < 64 * K; idx += 256 * 4) {
        float4 v = *reinterpret_cast<const float4*>(Ab + idx);
        int r = idx / K, k = idx - r * K;            // K % 4 == 0 -> float4 stays in-row
        *reinterpret_cast<float4*>(&As[r * KP + k]) = v;
    }
    __syncthreads();

    const int rg = threadIdx.x & 15;                 // row group: 4 rows
    const int cg = threadIdx.x >> 4;                 // col group: 8 cols
    float acc[4][8] = {};
    const float* Wb = W + (size_t)(cg * 8) * K;

    for (int kb = 0; kb < K; kb += 4) {
        float4 a0 = *reinterpret_cast<const float4*>(&As[(rg * 4 + 0) * KP + kb]);
        float4 a1 = *reinterpret_cast<const float4*>(&As[(rg * 4 + 1) * KP + kb]);
        float4 a2 = *reinterpret_cast<const float4*>(&As[(rg * 4 + 2) * KP + kb]);
        float4 a3 = *reinterpret_cast<const float4*>(&As[(rg * 4 + 3) * KP + kb]);
#pragma unroll
        for (int j = 0; j < 8; ++j) {
            float4 w = *reinterpret_cast<const float4*>(&Wb[j * K + kb]);
            acc[0][j] += a0.x * w.x + a0.y * w.y + a0.z * w.z + a0.w * w.w;
            acc[1][j] += a1.x * w.x + a1.y * w.y + a1.z * w.z + a1.w * w.w;
            acc[2][j] += a2.x * w.x + a2.y * w.y + a2.z * w.z + a2.w * w.w;
            acc[3][j] += a3.x * w.x + a3.y * w.y + a3.z * w.z + a3.w * w.w;
        }
    }

    const int rbase = row0 + rg * 4;
#pragma unroll
    for (int i = 0; i < 4; ++i) {
        int r = rbase + i;
        if (r >= N_NODES) break;
        float4 o0, o1;
        o0.x = acc[i][0] + bias[cg * 8 + 0]; o0.y = acc[i][1] + bias[cg * 8 + 1];
        o0.z = acc[i][2] + bias[cg * 8 + 2]; o0.w = acc[i][3] + bias[cg * 8 + 3];
        o1.x = acc[i][4] + bias[cg * 8 + 4]; o1.y = acc[i][5] + bias[cg * 8 + 5];
        o1.z = acc[i][6] + bias[cg * 8 + 6]; o1.w = acc[i][7] + bias[cg * 8 + 7];
        if (LEAKY) {
            o0.x = o0.x > 0.f ? o0.x : 0.01f * o0.x; o0.y = o0.y > 0.f ? o0.y : 0.01f * o0.y;
            o0.z = o0.z > 0.f ? o0.z : 0.01f * o0.z; o0.w = o0.w > 0.f ? o0.w : 0.01f * o0.w;
            o1.x = o1.x > 0.f ? o1.x : 0.01f * o1.x; o1.y = o1.y > 0.f ? o1.y : 0.01f * o1.y;
            o1.z = o1.z > 0.f ? o1.z : 0.01f * o1.z; o1.w = o1.w > 0.f ? o1.w : 0.01f * o1.w;
        }
        *reinterpret_cast<float4*>(&out[(size_t)r * FX + cg * 8])     = o0;
        *reinterpret_cast<float4*>(&out[(size_t)r * FX + cg * 8 + 4]) = o1;
    }
}

// ---------------------------------------------------------------- launch
extern "C" void kernel_launch(void* const* d_in, const int* in_sizes, int n_in,
                              void* d_out, int out_size, void* d_ws, size_t ws_size,
                              hipStream_t stream) {
    const float* x1  = (const float*)d_in[0];
    const int*   ei1 = (const int*)  d_in[1];
    const float* ea1 = (const float*)d_in[2];
    const float* x2  = (const float*)d_in[3];
    const int*   ei2 = (const int*)  d_in[4];
    const float* ea2 = (const float*)d_in[5];
    const float* WA  = (const float*)d_in[6];
    const float* bA  = (const float*)d_in[7];
    const float* WB  = (const float*)d_in[8];
    const float* bB  = (const float*)d_in[9];
    const float* fcW = (const float*)d_in[10];
    const float* fcb = (const float*)d_in[11];
    float* out = (float*)d_out;

    // workspace layout
    float* agg  = (float*)d_ws;                      // NPAD * FIN
    float* xb   = agg + (size_t)NPAD * FIN;          // NPAD * FX
    int* deg    = (int*)(xb + (size_t)NPAD * FX);    // N_NODES
    int* rowp   = deg + N_NODES;                     // N_NODES + 1
    int* cursor = rowp + N_NODES + 1;                // N_NODES
    int* csr    = cursor + N_NODES;                  // N_EDGES
    size_t needed = ((size_t)NPAD * (FIN + FX) + 3 * N_NODES + 1 + N_EDGES) * 4;
    if (ws_size < needed) return;                    // fail loudly (output stays poisoned)

    const dim3 b256(256);
    const dim3 gE((N_EDGES + 255) / 256);            // 6250
    const dim3 gZ((N_NODES * FE + 255) / 256);
    const dim3 gG((N_NODES + 7) / 8);                // 6250
    const dim3 gM((N_NODES + 63) / 64);              // 782

    for (int br = 0; br < 2; ++br) {
        const float* x  = br == 0 ? x1  : x2;
        const int*   ei = br == 0 ? ei1 : ei2;
        const float* ea = br == 0 ? ea1 : ea2;
        const float* Wl = br == 0 ? WA  : WB;
        const float* bl = br == 0 ? bA  : bB;

        // CSR build
        hipMemsetAsync(deg, 0, N_NODES * sizeof(int), stream);
        hist_kernel<<<gE, b256, 0, stream>>>(ei, deg);
        scan_kernel<<<1, 1024, 0, stream>>>(deg, rowp, cursor);
        fill_kernel<<<gE, b256, 0, stream>>>(ei, cursor, csr);

        // layer-invariant edge-attr aggregation into agg[:, 128:136]
        zero_ecols_kernel<<<gZ, b256, 0, stream>>>(agg);
        scatter_e_kernel<<<gE, b256, 0, stream>>>(ea, ei, agg);

        // 3 conv layers
        const float* xcur = x;
        for (int l = 0; l < 3; ++l) {
            gather_kernel<<<gG, b256, 0, stream>>>(xcur, rowp, csr, agg);
            gemm_kernel<FIN, 140, true><<<gM, b256, 0, stream>>>(
                agg, Wl + (size_t)l * FX * FIN, bl + (size_t)l * FX, xb);
            xcur = xb;
        }
        // final fc (no activation)
        gemm_kernel<FX, 132, false><<<gM, b256, 0, stream>>>(
            xb, fcW, fcb, out + (size_t)br * N_NODES * FX);
    }
}

// Round 2
// 1604.667 us; speedup vs baseline: 1.7945x; 1.7945x over previous
//
#include <hip/hip_runtime.h>

#define N_NODES 50000
#define N_EDGES 1600000
#define FX 128
#define FE 8
#define FIN 136          // FX + FE
#define NPAD 50048       // pad rows so 64-row GEMM tiles can over-read safely

// ---------------------------------------------------------------- CSR build
__global__ void hist_kernel(const int* __restrict__ ei, int* __restrict__ deg) {
    int e = blockIdx.x * 256 + threadIdx.x;
    if (e >= N_EDGES) return;
    atomicAdd(&deg[ei[N_EDGES + e]], 1);
}

__global__ void scan_kernel(const int* __restrict__ deg, int* __restrict__ row_ptr,
                            int* __restrict__ cursor) {
    __shared__ int sums[1024];
    const int n = N_NODES;
    int t = threadIdx.x;
    int chunk = (n + 1023) >> 10;                    // 49
    int i0 = t * chunk;
    int i1 = i0 + chunk; if (i1 > n) i1 = n;
    int s = 0;
    for (int i = i0; i < i1; ++i) s += deg[i];
    sums[t] = s;
    __syncthreads();
    // Hillis-Steele inclusive scan over 1024 partials
    for (int off = 1; off < 1024; off <<= 1) {
        int v = (t >= off) ? sums[t - off] : 0;
        __syncthreads();
        sums[t] += v;
        __syncthreads();
    }
    int running = sums[t] - s;                       // exclusive prefix for this chunk
    for (int i = i0; i < i1; ++i) {
        row_ptr[i] = running;
        cursor[i]  = running;
        running += deg[i];
    }
    if (t == 1023) row_ptr[n] = sums[1023];
}

__global__ void fill_kernel(const int* __restrict__ ei, int* __restrict__ cursor,
                            int* __restrict__ csr_src, int* __restrict__ csr_eid) {
    int e = blockIdx.x * 256 + threadIdx.x;
    if (e >= N_EDGES) return;
    int src = ei[e];
    int dst = ei[N_EDGES + e];
    int pos = atomicAdd(&cursor[dst], 1);
    csr_src[pos] = src;
    csr_eid[pos] = e;
}

// ------------------------------------------------- edge-attr aggregation (once per branch)
// CSR gather: 8 threads per node, lane = feature. Deterministic, no atomics.
__global__ void gather_e_kernel(const float* __restrict__ ea, const int* __restrict__ row_ptr,
                                const int* __restrict__ csr_eid, float* __restrict__ agg) {
    int node = blockIdx.x * 32 + (threadIdx.x >> 3);
    if (node >= N_NODES) return;
    int lane = threadIdx.x & 7;
    int start = row_ptr[node], end = row_ptr[node + 1];
    float acc = 0.f;
    int e = start;
    for (; e + 2 <= end; e += 2) {
        int e0 = csr_eid[e], e1 = csr_eid[e + 1];
        acc += ea[(size_t)e0 * FE + lane] + ea[(size_t)e1 * FE + lane];
    }
    if (e < end) {
        int e0 = csr_eid[e];
        acc += ea[(size_t)e0 * FE + lane];
    }
    agg[(size_t)node * FIN + FX + lane] = acc;
}

// ------------------------------------------------- sparse gather: agg_x[dst] = sum x[src]
// one 32-thread group per node, float4 per thread (32*4 = 128 features)
__global__ void gather_kernel(const float* __restrict__ x, const int* __restrict__ row_ptr,
                              const int* __restrict__ csr_src, float* __restrict__ agg) {
    int node = blockIdx.x * 8 + (threadIdx.x >> 5);
    if (node >= N_NODES) return;
    int lane = threadIdx.x & 31;
    int start = row_ptr[node], end = row_ptr[node + 1];
    float4 acc = {0.f, 0.f, 0.f, 0.f};
    int e = start;
    for (; e + 4 <= end; e += 4) {
        int s0 = csr_src[e], s1 = csr_src[e + 1], s2 = csr_src[e + 2], s3 = csr_src[e + 3];
        float4 v0 = *reinterpret_cast<const float4*>(&x[(size_t)s0 * FX + lane * 4]);
        float4 v1 = *reinterpret_cast<const float4*>(&x[(size_t)s1 * FX + lane * 4]);
        float4 v2 = *reinterpret_cast<const float4*>(&x[(size_t)s2 * FX + lane * 4]);
        float4 v3 = *reinterpret_cast<const float4*>(&x[(size_t)s3 * FX + lane * 4]);
        acc.x += v0.x + v1.x + v2.x + v3.x;
        acc.y += v0.y + v1.y + v2.y + v3.y;
        acc.z += v0.z + v1.z + v2.z + v3.z;
        acc.w += v0.w + v1.w + v2.w + v3.w;
    }
    for (; e < end; ++e) {
        int s = csr_src[e];
        float4 v = *reinterpret_cast<const float4*>(&x[(size_t)s * FX + lane * 4]);
        acc.x += v.x; acc.y += v.y; acc.z += v.z; acc.w += v.w;
    }
    *reinterpret_cast<float4*>(&agg[(size_t)node * FIN + lane * 4]) = acc;
}

// ------------------------------------------------- dense GEMM: out[N,128] = A[N,K] @ W[128,K]^T + b
// 64-row tile per block, 256 threads, 4x8 register tile per thread.
template <int K, int KP, bool LEAKY>
__global__ void gemm_kernel(const float* __restrict__ A, const float* __restrict__ W,
                            const float* __restrict__ bias, float* __restrict__ out) {
    __shared__ float As[64 * KP];
    const int row0 = blockIdx.x * 64;
    // cooperative load A tile (rows padded in ws, so no read guard needed)
    const float* Ab = A + (size_t)row0 * K;
    for (int idx = threadIdx.x * 4; idx < 64 * K; idx += 256 * 4) {
        float4 v = *reinterpret_cast<const float4*>(Ab + idx);
        int r = idx / K, k = idx - r * K;            // K % 4 == 0 -> float4 stays in-row
        *reinterpret_cast<float4*>(&As[r * KP + k]) = v;
    }
    __syncthreads();

    const int rg = threadIdx.x & 15;                 // row group: 4 rows
    const int cg = threadIdx.x >> 4;                 // col group: 8 cols
    float acc[4][8] = {};
    const float* Wb = W + (size_t)(cg * 8) * K;

    for (int kb = 0; kb < K; kb += 4) {
        float4 a0 = *reinterpret_cast<const float4*>(&As[(rg * 4 + 0) * KP + kb]);
        float4 a1 = *reinterpret_cast<const float4*>(&As[(rg * 4 + 1) * KP + kb]);
        float4 a2 = *reinterpret_cast<const float4*>(&As[(rg * 4 + 2) * KP + kb]);
        float4 a3 = *reinterpret_cast<const float4*>(&As[(rg * 4 + 3) * KP + kb]);
#pragma unroll
        for (int j = 0; j < 8; ++j) {
            float4 w = *reinterpret_cast<const float4*>(&Wb[j * K + kb]);
            acc[0][j] += a0.x * w.x + a0.y * w.y + a0.z * w.z + a0.w * w.w;
            acc[1][j] += a1.x * w.x + a1.y * w.y + a1.z * w.z + a1.w * w.w;
            acc[2][j] += a2.x * w.x + a2.y * w.y + a2.z * w.z + a2.w * w.w;
            acc[3][j] += a3.x * w.x + a3.y * w.y + a3.z * w.z + a3.w * w.w;
        }
    }

    const int rbase = row0 + rg * 4;
#pragma unroll
    for (int i = 0; i < 4; ++i) {
        int r = rbase + i;
        if (r >= N_NODES) break;
        float4 o0, o1;
        o0.x = acc[i][0] + bias[cg * 8 + 0]; o0.y = acc[i][1] + bias[cg * 8 + 1];
        o0.z = acc[i][2] + bias[cg * 8 + 2]; o0.w = acc[i][3] + bias[cg * 8 + 3];
        o1.x = acc[i][4] + bias[cg * 8 + 4]; o1.y = acc[i][5] + bias[cg * 8 + 5];
        o1.z = acc[i][6] + bias[cg * 8 + 6]; o1.w = acc[i][7] + bias[cg * 8 + 7];
        if (LEAKY) {
            o0.x = o0.x > 0.f ? o0.x : 0.01f * o0.x; o0.y = o0.y > 0.f ? o0.y : 0.01f * o0.y;
            o0.z = o0.z > 0.f ? o0.z : 0.01f * o0.z; o0.w = o0.w > 0.f ? o0.w : 0.01f * o0.w;
            o1.x = o1.x > 0.f ? o1.x : 0.01f * o1.x; o1.y = o1.y > 0.f ? o1.y : 0.01f * o1.y;
            o1.z = o1.z > 0.f ? o1.z : 0.01f * o1.z; o1.w = o1.w > 0.f ? o1.w : 0.01f * o1.w;
        }
        *reinterpret_cast<float4*>(&out[(size_t)r * FX + cg * 8])     = o0;
        *reinterpret_cast<float4*>(&out[(size_t)r * FX + cg * 8 + 4]) = o1;
    }
}

// ---------------------------------------------------------------- launch
extern "C" void kernel_launch(void* const* d_in, const int* in_sizes, int n_in,
                              void* d_out, int out_size, void* d_ws, size_t ws_size,
                              hipStream_t stream) {
    const float* x1  = (const float*)d_in[0];
    const int*   ei1 = (const int*)  d_in[1];
    const float* ea1 = (const float*)d_in[2];
    const float* x2  = (const float*)d_in[3];
    const int*   ei2 = (const int*)  d_in[4];
    const float* ea2 = (const float*)d_in[5];
    const float* WA  = (const float*)d_in[6];
    const float* bA  = (const float*)d_in[7];
    const float* WB  = (const float*)d_in[8];
    const float* bB  = (const float*)d_in[9];
    const float* fcW = (const float*)d_in[10];
    const float* fcb = (const float*)d_in[11];
    float* out = (float*)d_out;

    // workspace layout
    float* agg   = (float*)d_ws;                     // NPAD * FIN
    float* xb    = agg + (size_t)NPAD * FIN;         // NPAD * FX
    int* deg     = (int*)(xb + (size_t)NPAD * FX);   // N_NODES
    int* rowp    = deg + N_NODES;                    // N_NODES + 1
    int* cursor  = rowp + N_NODES + 1;               // N_NODES
    int* csr_src = cursor + N_NODES;                 // N_EDGES
    int* csr_eid = csr_src + N_EDGES;                // N_EDGES
    size_t needed = ((size_t)NPAD * (FIN + FX) + 3 * N_NODES + 1 + 2 * (size_t)N_EDGES) * 4;
    if (ws_size < needed) return;                    // fail loudly (output stays poisoned)

    const dim3 b256(256);
    const dim3 gE((N_EDGES + 255) / 256);            // 6250
    const dim3 gGE((N_NODES + 31) / 32);             // 1563
    const dim3 gG((N_NODES + 7) / 8);                // 6250
    const dim3 gM((N_NODES + 63) / 64);              // 782

    for (int br = 0; br < 2; ++br) {
        const float* x  = br == 0 ? x1  : x2;
        const int*   ei = br == 0 ? ei1 : ei2;
        const float* ea = br == 0 ? ea1 : ea2;
        const float* Wl = br == 0 ? WA  : WB;
        const float* bl = br == 0 ? bA  : bB;

        // CSR build
        hipMemsetAsync(deg, 0, N_NODES * sizeof(int), stream);
        hist_kernel<<<gE, b256, 0, stream>>>(ei, deg);
        scan_kernel<<<1, 1024, 0, stream>>>(deg, rowp, cursor);
        fill_kernel<<<gE, b256, 0, stream>>>(ei, cursor, csr_src, csr_eid);

        // layer-invariant edge-attr aggregation into agg[:, 128:136] (CSR gather, no atomics)
        gather_e_kernel<<<gGE, b256, 0, stream>>>(ea, rowp, csr_eid, agg);

        // 3 conv layers
        const float* xcur = x;
        for (int l = 0; l < 3; ++l) {
            gather_kernel<<<gG, b256, 0, stream>>>(xcur, rowp, csr_src, agg);
            gemm_kernel<FIN, 140, true><<<gM, b256, 0, stream>>>(
                agg, Wl + (size_t)l * FX * FIN, bl + (size_t)l * FX, xb);
            xcur = xb;
        }
        // final fc (no activation)
        gemm_kernel<FX, 132, false><<<gM, b256, 0, stream>>>(
            xb, fcW, fcb, out + (size_t)br * N_NODES * FX);
    }
}

// Round 3
// 1147.987 us; speedup vs baseline: 2.5083x; 1.3978x over previous
//
#include <hip/hip_runtime.h>

#define N_NODES 50000
#define N_EDGES 1600000
#define FX 128
#define FE 8
#define FIN 136          // FX + FE
#define NPAD 50048       // pad rows so 64-row GEMM tiles can over-read safely
#define NB_SCAN 196      // ceil(N_NODES / 256)

__device__ inline float bf2f(unsigned short h) {
    return __uint_as_float((unsigned)h << 16);
}
__device__ inline unsigned short f2bf(float f) {   // round-to-nearest-even
    unsigned u = __float_as_uint(f);
    u = (u + 0x7FFF + ((u >> 16) & 1)) >> 16;
    return (unsigned short)u;
}

// ---------------------------------------------------------------- CSR build
__global__ void hist_kernel(const int* __restrict__ ei, int* __restrict__ deg) {
    int e = blockIdx.x * 256 + threadIdx.x;
    if (e >= N_EDGES) return;
    atomicAdd(&deg[ei[N_EDGES + e]], 1);
}

__global__ void scan1_kernel(const int* __restrict__ deg, int* __restrict__ partial) {
    __shared__ int red[256];
    int i = blockIdx.x * 256 + threadIdx.x;
    red[threadIdx.x] = (i < N_NODES) ? deg[i] : 0;
    __syncthreads();
    for (int off = 128; off > 0; off >>= 1) {
        if (threadIdx.x < off) red[threadIdx.x] += red[threadIdx.x + off];
        __syncthreads();
    }
    if (threadIdx.x == 0) partial[blockIdx.x] = red[0];
}

__global__ void scan2_kernel(const int* __restrict__ partial, int* __restrict__ base,
                             int* __restrict__ row_ptr) {
    __shared__ int s[256];
    int t = threadIdx.x;
    int v = (t < NB_SCAN) ? partial[t] : 0;
    s[t] = v;
    __syncthreads();
    for (int off = 1; off < 256; off <<= 1) {
        int u = (t >= off) ? s[t - off] : 0;
        __syncthreads();
        s[t] += u;
        __syncthreads();
    }
    if (t < NB_SCAN) base[t] = s[t] - v;             // exclusive prefix per block
    if (t == 255) row_ptr[N_NODES] = s[255];         // total
}

__global__ void scan3_kernel(const int* __restrict__ deg, const int* __restrict__ base,
                             int* __restrict__ row_ptr, int* __restrict__ cursor) {
    __shared__ int s[256];
    int i = blockIdx.x * 256 + threadIdx.x;
    int t = threadIdx.x;
    int v = (i < N_NODES) ? deg[i] : 0;
    s[t] = v;
    __syncthreads();
    for (int off = 1; off < 256; off <<= 1) {
        int u = (t >= off) ? s[t - off] : 0;
        __syncthreads();
        s[t] += u;
        __syncthreads();
    }
    if (i < N_NODES) {
        int ex = base[blockIdx.x] + s[t] - v;
        row_ptr[i] = ex;
        cursor[i]  = ex;
    }
}

__global__ void fill_kernel(const int* __restrict__ ei, int* __restrict__ cursor,
                            int2* __restrict__ csr) {
    int e = blockIdx.x * 256 + threadIdx.x;
    if (e >= N_EDGES) return;
    int src = ei[e];
    int dst = ei[N_EDGES + e];
    int pos = atomicAdd(&cursor[dst], 1);
    csr[pos] = make_int2(src, e);                    // one 8B store per edge
}

// ------------------------------------------------- edge-attr aggregation (once per branch)
__global__ void gather_e_kernel(const float* __restrict__ ea, const int* __restrict__ row_ptr,
                                const int2* __restrict__ csr, float* __restrict__ agg) {
    int node = blockIdx.x * 32 + (threadIdx.x >> 3);
    if (node >= N_NODES) return;
    int lane = threadIdx.x & 7;
    int start = row_ptr[node], end = row_ptr[node + 1];
    float acc = 0.f;
    int e = start;
    for (; e + 2 <= end; e += 2) {
        int e0 = csr[e].y, e1 = csr[e + 1].y;
        acc += ea[(size_t)e0 * FE + lane] + ea[(size_t)e1 * FE + lane];
    }
    if (e < end) acc += ea[(size_t)csr[e].y * FE + lane];
    agg[(size_t)node * FIN + FX + lane] = acc;
}

// ---------------------------------------------------------------- fp32 -> bf16 convert
__global__ void f2bf_kernel(const float* __restrict__ in, unsigned short* __restrict__ out16) {
    int i = blockIdx.x * 256 + threadIdx.x;          // over N_NODES*FX/4
    if (i >= N_NODES * FX / 4) return;
    float4 v = reinterpret_cast<const float4*>(in)[i];
    ushort4 o;
    o.x = f2bf(v.x); o.y = f2bf(v.y); o.z = f2bf(v.z); o.w = f2bf(v.w);
    reinterpret_cast<ushort4*>(out16)[i] = o;
}

// ------------------------------------------------- sparse gather: agg_x[dst] = sum x[src]
// one 32-thread group per node; bf16 rows (256B), 8B per lane, fp32 accumulation
__global__ void gather_kernel(const unsigned short* __restrict__ x16,
                              const int* __restrict__ row_ptr,
                              const int2* __restrict__ csr, float* __restrict__ agg) {
    int node = blockIdx.x * 8 + (threadIdx.x >> 5);
    if (node >= N_NODES) return;
    int lane = threadIdx.x & 31;
    int start = row_ptr[node], end = row_ptr[node + 1];
    float a0 = 0.f, a1 = 0.f, a2 = 0.f, a3 = 0.f;
    int e = start;
    for (; e + 4 <= end; e += 4) {
        int s0 = csr[e].x, s1 = csr[e + 1].x, s2 = csr[e + 2].x, s3 = csr[e + 3].x;
        ushort4 v0 = *reinterpret_cast<const ushort4*>(&x16[(size_t)s0 * FX + lane * 4]);
        ushort4 v1 = *reinterpret_cast<const ushort4*>(&x16[(size_t)s1 * FX + lane * 4]);
        ushort4 v2 = *reinterpret_cast<const ushort4*>(&x16[(size_t)s2 * FX + lane * 4]);
        ushort4 v3 = *reinterpret_cast<const ushort4*>(&x16[(size_t)s3 * FX + lane * 4]);
        a0 += bf2f(v0.x) + bf2f(v1.x) + bf2f(v2.x) + bf2f(v3.x);
        a1 += bf2f(v0.y) + bf2f(v1.y) + bf2f(v2.y) + bf2f(v3.y);
        a2 += bf2f(v0.z) + bf2f(v1.z) + bf2f(v2.z) + bf2f(v3.z);
        a3 += bf2f(v0.w) + bf2f(v1.w) + bf2f(v2.w) + bf2f(v3.w);
    }
    for (; e < end; ++e) {
        ushort4 v = *reinterpret_cast<const ushort4*>(&x16[(size_t)csr[e].x * FX + lane * 4]);
        a0 += bf2f(v.x); a1 += bf2f(v.y); a2 += bf2f(v.z); a3 += bf2f(v.w);
    }
    float4 acc = {a0, a1, a2, a3};
    *reinterpret_cast<float4*>(&agg[(size_t)node * FIN + lane * 4]) = acc;
}

// ------------------------------------------------- dense GEMM: out[N,128] = A[N,K] @ W[128,K]^T + b
// 64-row tile, 256 threads, 4x8 register tile. A may be fp32 or bf16; out may be fp32 or bf16.
template <int K, int KP, bool LEAKY, bool ABF16, bool OBF16>
__global__ void gemm_kernel(const void* __restrict__ Av, const float* __restrict__ W,
                            const float* __restrict__ bias, void* __restrict__ outv) {
    __shared__ float As[64 * KP];
    const int row0 = blockIdx.x * 64;
    if constexpr (ABF16) {
        const unsigned short* Ab = (const unsigned short*)Av + (size_t)row0 * K;
        for (int idx = threadIdx.x * 4; idx < 64 * K; idx += 256 * 4) {
            ushort4 v = *reinterpret_cast<const ushort4*>(Ab + idx);
            int r = idx / K, k = idx - r * K;
            float4 f = {bf2f(v.x), bf2f(v.y), bf2f(v.z), bf2f(v.w)};
            *reinterpret_cast<float4*>(&As[r * KP + k]) = f;
        }
    } else {
        const float* Ab = (const float*)Av + (size_t)row0 * K;
        for (int idx = threadIdx.x * 4; idx < 64 * K; idx += 256 * 4) {
            float4 v = *reinterpret_cast<const float4*>(Ab + idx);
            int r = idx / K, k = idx - r * K;
            *reinterpret_cast<float4*>(&As[r * KP + k]) = v;
        }
    }
    __syncthreads();

    const int rg = threadIdx.x & 15;                 // row group: 4 rows
    const int cg = threadIdx.x >> 4;                 // col group: 8 cols
    float acc[4][8] = {};
    const float* Wb = W + (size_t)(cg * 8) * K;

    for (int kb = 0; kb < K; kb += 4) {
        float4 a0 = *reinterpret_cast<const float4*>(&As[(rg * 4 + 0) * KP + kb]);
        float4 a1 = *reinterpret_cast<const float4*>(&As[(rg * 4 + 1) * KP + kb]);
        float4 a2 = *reinterpret_cast<const float4*>(&As[(rg * 4 + 2) * KP + kb]);
        float4 a3 = *reinterpret_cast<const float4*>(&As[(rg * 4 + 3) * KP + kb]);
#pragma unroll
        for (int j = 0; j < 8; ++j) {
            float4 w = *reinterpret_cast<const float4*>(&Wb[j * K + kb]);
            acc[0][j] += a0.x * w.x + a0.y * w.y + a0.z * w.z + a0.w * w.w;
            acc[1][j] += a1.x * w.x + a1.y * w.y + a1.z * w.z + a1.w * w.w;
            acc[2][j] += a2.x * w.x + a2.y * w.y + a2.z * w.z + a2.w * w.w;
            acc[3][j] += a3.x * w.x + a3.y * w.y + a3.z * w.z + a3.w * w.w;
        }
    }

    const int rbase = row0 + rg * 4;
#pragma unroll
    for (int i = 0; i < 4; ++i) {
        int r = rbase + i;
        if (r >= N_NODES) break;
        float o[8];
#pragma unroll
        for (int j = 0; j < 8; ++j) {
            float v = acc[i][j] + bias[cg * 8 + j];
            if (LEAKY) v = v > 0.f ? v : 0.01f * v;
            o[j] = v;
        }
        if constexpr (OBF16) {
            unsigned short* op = (unsigned short*)outv + (size_t)r * FX + cg * 8;
            ushort4 lo = {f2bf(o[0]), f2bf(o[1]), f2bf(o[2]), f2bf(o[3])};
            ushort4 hi = {f2bf(o[4]), f2bf(o[5]), f2bf(o[6]), f2bf(o[7])};
            *reinterpret_cast<ushort4*>(op)     = lo;
            *reinterpret_cast<ushort4*>(op + 4) = hi;
        } else {
            float* op = (float*)outv + (size_t)r * FX + cg * 8;
            float4 lo = {o[0], o[1], o[2], o[3]};
            float4 hi = {o[4], o[5], o[6], o[7]};
            *reinterpret_cast<float4*>(op)     = lo;
            *reinterpret_cast<float4*>(op + 4) = hi;
        }
    }
}

// ---------------------------------------------------------------- launch
extern "C" void kernel_launch(void* const* d_in, const int* in_sizes, int n_in,
                              void* d_out, int out_size, void* d_ws, size_t ws_size,
                              hipStream_t stream) {
    const float* x1  = (const float*)d_in[0];
    const int*   ei1 = (const int*)  d_in[1];
    const float* ea1 = (const float*)d_in[2];
    const float* x2  = (const float*)d_in[3];
    const int*   ei2 = (const int*)  d_in[4];
    const float* ea2 = (const float*)d_in[5];
    const float* WA  = (const float*)d_in[6];
    const float* bA  = (const float*)d_in[7];
    const float* WB  = (const float*)d_in[8];
    const float* bB  = (const float*)d_in[9];
    const float* fcW = (const float*)d_in[10];
    const float* fcb = (const float*)d_in[11];
    float* out = (float*)d_out;

    // workspace layout (8B-aligned int2 region placed before odd-sized int arrays)
    float* agg           = (float*)d_ws;                         // NPAD*FIN f32
    unsigned short* h16  = (unsigned short*)(agg + (size_t)NPAD * FIN);  // NPAD*FX bf16
    int2* csr            = (int2*)(h16 + (size_t)NPAD * FX);     // N_EDGES int2
    int* deg             = (int*)(csr + N_EDGES);                // N_NODES
    int* rowp            = deg + N_NODES;                        // N_NODES+1
    int* cursor          = rowp + N_NODES + 1;                   // N_NODES
    int* partial         = cursor + N_NODES;                     // NB_SCAN
    int* base            = partial + NB_SCAN;                    // NB_SCAN
    size_t needed = (size_t)(base + NB_SCAN) - (size_t)d_ws;
    if (ws_size < needed) return;                                // output stays poisoned

    const dim3 b256(256);
    const dim3 gE((N_EDGES + 255) / 256);            // 6250
    const dim3 gS(NB_SCAN);                          // 196
    const dim3 gGE((N_NODES + 31) / 32);             // 1563
    const dim3 gG((N_NODES + 7) / 8);                // 6250
    const dim3 gC((N_NODES * FX / 4 + 255) / 256);   // 6250
    const dim3 gM((N_NODES + 63) / 64);              // 782

    for (int br = 0; br < 2; ++br) {
        const float* x  = br == 0 ? x1  : x2;
        const int*   ei = br == 0 ? ei1 : ei2;
        const float* ea = br == 0 ? ea1 : ea2;
        const float* Wl = br == 0 ? WA  : WB;
        const float* bl = br == 0 ? bA  : bB;

        // CSR build
        hipMemsetAsync(deg, 0, N_NODES * sizeof(int), stream);
        hist_kernel<<<gE, b256, 0, stream>>>(ei, deg);
        scan1_kernel<<<gS, b256, 0, stream>>>(deg, partial);
        scan2_kernel<<<1, b256, 0, stream>>>(partial, base, rowp);
        scan3_kernel<<<gS, b256, 0, stream>>>(deg, base, rowp, cursor);
        fill_kernel<<<gE, b256, 0, stream>>>(ei, cursor, csr);

        // layer-invariant edge-attr aggregation into agg[:, 128:136]
        gather_e_kernel<<<gGE, b256, 0, stream>>>(ea, rowp, csr, agg);

        // input features -> bf16
        f2bf_kernel<<<gC, b256, 0, stream>>>(x, h16);

        // 3 conv layers: gather (bf16 in, fp32 agg) + GEMM (fp32 A, bf16 out)
        for (int l = 0; l < 3; ++l) {
            gather_kernel<<<gG, b256, 0, stream>>>(h16, rowp, csr, agg);
            gemm_kernel<FIN, 140, true, false, true><<<gM, b256, 0, stream>>>(
                agg, Wl + (size_t)l * FX * FIN, bl + (size_t)l * FX, h16);
        }
        // final fc: bf16 A, fp32 out, no activation
        gemm_kernel<FX, 132, false, true, false><<<gM, b256, 0, stream>>>(
            h16, fcW, fcb, out + (size_t)br * N_NODES * FX);
    }
}

// Round 4
// 1059.221 us; speedup vs baseline: 2.7185x; 1.0838x over previous
//
#include <hip/hip_runtime.h>

#define N_NODES 50000
#define N_EDGES 1600000
#define FX 128
#define FE 8
#define FIN 136          // FX + FE
#define NPAD 50048       // pad rows so 64-row GEMM tiles can over-read safely
#define NB_SCAN 196      // ceil(N_NODES / 256)
#define NXCD 8
#define NPC 6250         // nodes per XCD class (N_NODES / NXCD)
#define FCHUNK 2048      // edges per chunk in fill

__device__ inline float bf2f(unsigned short h) {
    return __uint_as_float((unsigned)h << 16);
}
__device__ inline unsigned short f2bf(float f) {   // round-to-nearest-even
    unsigned u = __float_as_uint(f);
    u = (u + 0x7FFF + ((u >> 16) & 1)) >> 16;
    return (unsigned short)u;
}

// ---------------------------------------------------------------- CSR build
__global__ void hist_kernel(const int* __restrict__ ei, int* __restrict__ deg) {
    int e = blockIdx.x * 256 + threadIdx.x;
    if (e >= N_EDGES) return;
    atomicAdd(&deg[ei[N_EDGES + e]], 1);
}

__global__ void scan1_kernel(const int* __restrict__ deg, int* __restrict__ partial) {
    __shared__ int red[256];
    int i = blockIdx.x * 256 + threadIdx.x;
    red[threadIdx.x] = (i < N_NODES) ? deg[i] : 0;
    __syncthreads();
    for (int off = 128; off > 0; off >>= 1) {
        if (threadIdx.x < off) red[threadIdx.x] += red[threadIdx.x + off];
        __syncthreads();
    }
    if (threadIdx.x == 0) partial[blockIdx.x] = red[0];
}

__global__ void scan2_kernel(const int* __restrict__ partial, int* __restrict__ base,
                             int* __restrict__ row_ptr) {
    __shared__ int s[256];
    int t = threadIdx.x;
    int v = (t < NB_SCAN) ? partial[t] : 0;
    s[t] = v;
    __syncthreads();
    for (int off = 1; off < 256; off <<= 1) {
        int u = (t >= off) ? s[t - off] : 0;
        __syncthreads();
        s[t] += u;
        __syncthreads();
    }
    if (t < NB_SCAN) base[t] = s[t] - v;             // exclusive prefix per block
    if (t == 255) row_ptr[N_NODES] = s[255];         // total
}

__global__ void scan3_kernel(const int* __restrict__ deg, const int* __restrict__ base,
                             int* __restrict__ row_ptr, int* __restrict__ cursor) {
    __shared__ int s[256];
    int i = blockIdx.x * 256 + threadIdx.x;
    int t = threadIdx.x;
    int v = (i < N_NODES) ? deg[i] : 0;
    s[t] = v;
    __syncthreads();
    for (int off = 1; off < 256; off <<= 1) {
        int u = (t >= off) ? s[t - off] : 0;
        __syncthreads();
        s[t] += u;
        __syncthreads();
    }
    if (i < N_NODES) {
        int ex = base[blockIdx.x] + s[t] - v;
        row_ptr[i] = ex;
        cursor[i]  = ex;
    }
}

// XCD-partitioned fill: each chunk of edges is scanned by 8 blocks (one per XCD,
// blockIdx&7 -> XCD by round-robin dispatch); class c writes only dst in
// [c*NPC, (c+1)*NPC) so each XCD's CSR window (~1.6 MB) stays in its private L2
// and lines are filled before eviction. dst re-reads are non-temporal.
__global__ void fill_kernel(const int* __restrict__ ei, int* __restrict__ cursor,
                            int2* __restrict__ csr) {
    int chunk = blockIdx.x >> 3;
    int cls   = blockIdx.x & 7;
    int e0 = chunk * FCHUNK;
    int e1 = e0 + FCHUNK; if (e1 > N_EDGES) e1 = N_EDGES;
    int lo = cls * NPC, hi = lo + NPC;
    for (int e = e0 + threadIdx.x; e < e1; e += 256) {
        int dst = __builtin_nontemporal_load(&ei[N_EDGES + e]);
        if (dst >= lo && dst < hi) {
            int src = ei[e];
            int pos = atomicAdd(&cursor[dst], 1);
            csr[pos] = make_int2(src, e);
        }
    }
}

// ------------------------------------------------- edge-attr aggregation (once per branch)
__global__ void gather_e_kernel(const float* __restrict__ ea, const int* __restrict__ row_ptr,
                                const int2* __restrict__ csr, float* __restrict__ agg) {
    int node = blockIdx.x * 32 + (threadIdx.x >> 3);
    if (node >= N_NODES) return;
    int lane = threadIdx.x & 7;
    int start = row_ptr[node], end = row_ptr[node + 1];
    float acc = 0.f;
    int e = start;
    for (; e + 2 <= end; e += 2) {
        int e0 = csr[e].y, e1 = csr[e + 1].y;
        acc += ea[(size_t)e0 * FE + lane] + ea[(size_t)e1 * FE + lane];
    }
    if (e < end) acc += ea[(size_t)csr[e].y * FE + lane];
    agg[(size_t)node * FIN + FX + lane] = acc;
}

// ---------------------------------------------------------------- fp32 -> bf16 convert
__global__ void f2bf_kernel(const float* __restrict__ in, unsigned short* __restrict__ out16) {
    int i = blockIdx.x * 256 + threadIdx.x;          // over N_NODES*FX/4
    if (i >= N_NODES * FX / 4) return;
    float4 v = reinterpret_cast<const float4*>(in)[i];
    ushort4 o;
    o.x = f2bf(v.x); o.y = f2bf(v.y); o.z = f2bf(v.z); o.w = f2bf(v.w);
    reinterpret_cast<ushort4*>(out16)[i] = o;
}

// ------------------------------------------------- sparse gather: agg_x[dst] = sum x[src]
// 16 lanes per node, 16B (8 bf16) per lane per row; fp32 accumulation.
__global__ void gather_kernel(const unsigned short* __restrict__ x16,
                              const int* __restrict__ row_ptr,
                              const int2* __restrict__ csr, float* __restrict__ agg) {
    int node = blockIdx.x * 16 + (threadIdx.x >> 4);
    if (node >= N_NODES) return;
    int lane = threadIdx.x & 15;
    int start = row_ptr[node], end = row_ptr[node + 1];
    const uint4* xr = reinterpret_cast<const uint4*>(x16);   // 16 uint4 per row
    float a[8] = {};
    int e = start;
    for (; e + 4 <= end; e += 4) {
        uint4 v0 = xr[(size_t)csr[e].x     * 16 + lane];
        uint4 v1 = xr[(size_t)csr[e + 1].x * 16 + lane];
        uint4 v2 = xr[(size_t)csr[e + 2].x * 16 + lane];
        uint4 v3 = xr[(size_t)csr[e + 3].x * 16 + lane];
#pragma unroll
        for (int q = 0; q < 4; ++q) {
            unsigned u0 = (&v0.x)[q], u1 = (&v1.x)[q], u2 = (&v2.x)[q], u3 = (&v3.x)[q];
            a[q * 2]     += __uint_as_float(u0 << 16) + __uint_as_float(u1 << 16)
                          + __uint_as_float(u2 << 16) + __uint_as_float(u3 << 16);
            a[q * 2 + 1] += __uint_as_float(u0 & 0xffff0000u) + __uint_as_float(u1 & 0xffff0000u)
                          + __uint_as_float(u2 & 0xffff0000u) + __uint_as_float(u3 & 0xffff0000u);
        }
    }
    for (; e < end; ++e) {
        uint4 v = xr[(size_t)csr[e].x * 16 + lane];
#pragma unroll
        for (int q = 0; q < 4; ++q) {
            unsigned u = (&v.x)[q];
            a[q * 2]     += __uint_as_float(u << 16);
            a[q * 2 + 1] += __uint_as_float(u & 0xffff0000u);
        }
    }
    float* op = &agg[(size_t)node * FIN + lane * 8];
    *reinterpret_cast<float4*>(op)     = make_float4(a[0], a[1], a[2], a[3]);
    *reinterpret_cast<float4*>(op + 4) = make_float4(a[4], a[5], a[6], a[7]);
}

// ------------------------------------------------- dense GEMM: out[N,128] = A[N,K] @ W[128,K]^T + b
// 64-row tile, 256 threads, 4x8 register tile. A may be fp32 or bf16; out may be fp32 or bf16.
template <int K, int KP, bool LEAKY, bool ABF16, bool OBF16>
__global__ void gemm_kernel(const void* __restrict__ Av, const float* __restrict__ W,
                            const float* __restrict__ bias, void* __restrict__ outv) {
    __shared__ float As[64 * KP];
    const int row0 = blockIdx.x * 64;
    if constexpr (ABF16) {
        const unsigned short* Ab = (const unsigned short*)Av + (size_t)row0 * K;
        for (int idx = threadIdx.x * 4; idx < 64 * K; idx += 256 * 4) {
            ushort4 v = *reinterpret_cast<const ushort4*>(Ab + idx);
            int r = idx / K, k = idx - r * K;
            float4 f = {bf2f(v.x), bf2f(v.y), bf2f(v.z), bf2f(v.w)};
            *reinterpret_cast<float4*>(&As[r * KP + k]) = f;
        }
    } else {
        const float* Ab = (const float*)Av + (size_t)row0 * K;
        for (int idx = threadIdx.x * 4; idx < 64 * K; idx += 256 * 4) {
            float4 v = *reinterpret_cast<const float4*>(Ab + idx);
            int r = idx / K, k = idx - r * K;
            *reinterpret_cast<float4*>(&As[r * KP + k]) = v;
        }
    }
    __syncthreads();

    const int rg = threadIdx.x & 15;                 // row group: 4 rows
    const int cg = threadIdx.x >> 4;                 // col group: 8 cols
    float acc[4][8] = {};
    const float* Wb = W + (size_t)(cg * 8) * K;

    for (int kb = 0; kb < K; kb += 4) {
        float4 a0 = *reinterpret_cast<const float4*>(&As[(rg * 4 + 0) * KP + kb]);
        float4 a1 = *reinterpret_cast<const float4*>(&As[(rg * 4 + 1) * KP + kb]);
        float4 a2 = *reinterpret_cast<const float4*>(&As[(rg * 4 + 2) * KP + kb]);
        float4 a3 = *reinterpret_cast<const float4*>(&As[(rg * 4 + 3) * KP + kb]);
#pragma unroll
        for (int j = 0; j < 8; ++j) {
            float4 w = *reinterpret_cast<const float4*>(&Wb[j * K + kb]);
            acc[0][j] += a0.x * w.x + a0.y * w.y + a0.z * w.z + a0.w * w.w;
            acc[1][j] += a1.x * w.x + a1.y * w.y + a1.z * w.z + a1.w * w.w;
            acc[2][j] += a2.x * w.x + a2.y * w.y + a2.z * w.z + a2.w * w.w;
            acc[3][j] += a3.x * w.x + a3.y * w.y + a3.z * w.z + a3.w * w.w;
        }
    }

    const int rbase = row0 + rg * 4;
#pragma unroll
    for (int i = 0; i < 4; ++i) {
        int r = rbase + i;
        if (r >= N_NODES) break;
        float o[8];
#pragma unroll
        for (int j = 0; j < 8; ++j) {
            float v = acc[i][j] + bias[cg * 8 + j];
            if (LEAKY) v = v > 0.f ? v : 0.01f * v;
            o[j] = v;
        }
        if constexpr (OBF16) {
            unsigned short* op = (unsigned short*)outv + (size_t)r * FX + cg * 8;
            ushort4 lo = {f2bf(o[0]), f2bf(o[1]), f2bf(o[2]), f2bf(o[3])};
            ushort4 hi = {f2bf(o[4]), f2bf(o[5]), f2bf(o[6]), f2bf(o[7])};
            *reinterpret_cast<ushort4*>(op)     = lo;
            *reinterpret_cast<ushort4*>(op + 4) = hi;
        } else {
            float* op = (float*)outv + (size_t)r * FX + cg * 8;
            float4 lo = {o[0], o[1], o[2], o[3]};
            float4 hi = {o[4], o[5], o[6], o[7]};
            *reinterpret_cast<float4*>(op)     = lo;
            *reinterpret_cast<float4*>(op + 4) = hi;
        }
    }
}

// ---------------------------------------------------------------- launch
extern "C" void kernel_launch(void* const* d_in, const int* in_sizes, int n_in,
                              void* d_out, int out_size, void* d_ws, size_t ws_size,
                              hipStream_t stream) {
    const float* x1  = (const float*)d_in[0];
    const int*   ei1 = (const int*)  d_in[1];
    const float* ea1 = (const float*)d_in[2];
    const float* x2  = (const float*)d_in[3];
    const int*   ei2 = (const int*)  d_in[4];
    const float* ea2 = (const float*)d_in[5];
    const float* WA  = (const float*)d_in[6];
    const float* bA  = (const float*)d_in[7];
    const float* WB  = (const float*)d_in[8];
    const float* bB  = (const float*)d_in[9];
    const float* fcW = (const float*)d_in[10];
    const float* fcb = (const float*)d_in[11];
    float* out = (float*)d_out;

    // workspace layout (8B-aligned int2 region placed before odd-sized int arrays)
    float* agg           = (float*)d_ws;                         // NPAD*FIN f32
    unsigned short* h16  = (unsigned short*)(agg + (size_t)NPAD * FIN);  // NPAD*FX bf16
    int2* csr            = (int2*)(h16 + (size_t)NPAD * FX);     // N_EDGES int2
    int* deg             = (int*)(csr + N_EDGES);                // N_NODES
    int* rowp            = deg + N_NODES;                        // N_NODES+1
    int* cursor          = rowp + N_NODES + 1;                   // N_NODES
    int* partial         = cursor + N_NODES;                     // NB_SCAN
    int* base            = partial + NB_SCAN;                    // NB_SCAN
    size_t needed = (size_t)(base + NB_SCAN) - (size_t)d_ws;
    if (ws_size < needed) return;                                // output stays poisoned

    const dim3 b256(256);
    const dim3 gE((N_EDGES + 255) / 256);            // 6250
    const dim3 gF(((N_EDGES + FCHUNK - 1) / FCHUNK) * NXCD);  // 782*8
    const dim3 gS(NB_SCAN);                          // 196
    const dim3 gGE((N_NODES + 31) / 32);             // 1563
    const dim3 gG((N_NODES + 15) / 16);              // 3125
    const dim3 gC((N_NODES * FX / 4 + 255) / 256);   // 6250
    const dim3 gM((N_NODES + 63) / 64);              // 782

    for (int br = 0; br < 2; ++br) {
        const float* x  = br == 0 ? x1  : x2;
        const int*   ei = br == 0 ? ei1 : ei2;
        const float* ea = br == 0 ? ea1 : ea2;
        const float* Wl = br == 0 ? WA  : WB;
        const float* bl = br == 0 ? bA  : bB;

        // CSR build
        hipMemsetAsync(deg, 0, N_NODES * sizeof(int), stream);
        hist_kernel<<<gE, b256, 0, stream>>>(ei, deg);
        scan1_kernel<<<gS, b256, 0, stream>>>(deg, partial);
        scan2_kernel<<<1, b256, 0, stream>>>(partial, base, rowp);
        scan3_kernel<<<gS, b256, 0, stream>>>(deg, base, rowp, cursor);
        fill_kernel<<<gF, b256, 0, stream>>>(ei, cursor, csr);

        // layer-invariant edge-attr aggregation into agg[:, 128:136]
        gather_e_kernel<<<gGE, b256, 0, stream>>>(ea, rowp, csr, agg);

        // input features -> bf16
        f2bf_kernel<<<gC, b256, 0, stream>>>(x, h16);

        // 3 conv layers: gather (bf16 in, fp32 agg) + GEMM (fp32 A, bf16 out)
        for (int l = 0; l < 3; ++l) {
            gather_kernel<<<gG, b256, 0, stream>>>(h16, rowp, csr, agg);
            gemm_kernel<FIN, 140, true, false, true><<<gM, b256, 0, stream>>>(
                agg, Wl + (size_t)l * FX * FIN, bl + (size_t)l * FX, h16);
        }
        // final fc: bf16 A, fp32 out, no activation
        gemm_kernel<FX, 132, false, true, false><<<gM, b256, 0, stream>>>(
            h16, fcW, fcb, out + (size_t)br * N_NODES * FX);
    }
}

// Round 5
// 796.653 us; speedup vs baseline: 3.6145x; 1.3296x over previous
//
#include <hip/hip_runtime.h>

#define N_NODES 50000
#define N_EDGES 1600000
#define FX 128
#define FE 8
#define FIN 136          // FX + FE
#define NPAD 50048       // pad rows so 64-row GEMM tiles can over-read safely
#define NB_SCAN 196      // ceil(N_NODES / 256)
#define NXCD 8
#define NPC 6250         // nodes per XCD class (N_NODES / NXCD)
#define FCHUNK 2048      // edges per chunk in fill
#define NCHUNK ((N_EDGES + FCHUNK - 1) / FCHUNK)   // 782

typedef short short8v __attribute__((ext_vector_type(8)));
typedef float float4v __attribute__((ext_vector_type(4)));

__device__ inline float bf2f(unsigned short h) {
    return __uint_as_float((unsigned)h << 16);
}
__device__ inline unsigned short f2bf(float f) {   // round-to-nearest-even
    unsigned u = __float_as_uint(f);
    u = (u + 0x7FFF + ((u >> 16) & 1)) >> 16;
    return (unsigned short)u;
}

// ---------------------------------------------------------------- CSR build (y = branch)
__global__ void hist_kernel(const int* __restrict__ ei0, const int* __restrict__ ei1,
                            int* __restrict__ deg0, int* __restrict__ deg1) {
    const int* ei = blockIdx.y ? ei1 : ei0;
    int* deg      = blockIdx.y ? deg1 : deg0;
    int e = blockIdx.x * 256 + threadIdx.x;
    if (e >= N_EDGES) return;
    atomicAdd(&deg[__builtin_nontemporal_load(&ei[N_EDGES + e])], 1);
}

__global__ void scan1_kernel(const int* __restrict__ deg0, const int* __restrict__ deg1,
                             int* __restrict__ p0, int* __restrict__ p1) {
    const int* deg = blockIdx.y ? deg1 : deg0;
    int* partial   = blockIdx.y ? p1 : p0;
    __shared__ int red[256];
    int i = blockIdx.x * 256 + threadIdx.x;
    red[threadIdx.x] = (i < N_NODES) ? deg[i] : 0;
    __syncthreads();
    for (int off = 128; off > 0; off >>= 1) {
        if (threadIdx.x < off) red[threadIdx.x] += red[threadIdx.x + off];
        __syncthreads();
    }
    if (threadIdx.x == 0) partial[blockIdx.x] = red[0];
}

__global__ void scan2_kernel(const int* __restrict__ p0, const int* __restrict__ p1,
                             int* __restrict__ base0, int* __restrict__ base1,
                             int* __restrict__ rp0, int* __restrict__ rp1) {
    const int* partial = blockIdx.y ? p1 : p0;
    int* base          = blockIdx.y ? base1 : base0;
    int* row_ptr       = blockIdx.y ? rp1 : rp0;
    __shared__ int s[256];
    int t = threadIdx.x;
    int v = (t < NB_SCAN) ? partial[t] : 0;
    s[t] = v;
    __syncthreads();
    for (int off = 1; off < 256; off <<= 1) {
        int u = (t >= off) ? s[t - off] : 0;
        __syncthreads();
        s[t] += u;
        __syncthreads();
    }
    if (t < NB_SCAN) base[t] = s[t] - v;
    if (t == 255) row_ptr[N_NODES] = s[255];
}

__global__ void scan3_kernel(const int* __restrict__ deg0, const int* __restrict__ deg1,
                             const int* __restrict__ base0, const int* __restrict__ base1,
                             int* __restrict__ rp0, int* __restrict__ rp1,
                             int* __restrict__ cur0, int* __restrict__ cur1) {
    const int* deg  = blockIdx.y ? deg1 : deg0;
    const int* base = blockIdx.y ? base1 : base0;
    int* row_ptr    = blockIdx.y ? rp1 : rp0;
    int* cursor     = blockIdx.y ? cur1 : cur0;
    __shared__ int s[256];
    int i = blockIdx.x * 256 + threadIdx.x;
    int t = threadIdx.x;
    int v = (i < N_NODES) ? deg[i] : 0;
    s[t] = v;
    __syncthreads();
    for (int off = 1; off < 256; off <<= 1) {
        int u = (t >= off) ? s[t - off] : 0;
        __syncthreads();
        s[t] += u;
        __syncthreads();
    }
    if (i < N_NODES) {
        int ex = base[blockIdx.x] + s[t] - v;
        row_ptr[i] = ex;
        cursor[i]  = ex;
    }
}

// XCD-partitioned fill (see R3 note): class c writes only dst in [c*NPC,(c+1)*NPC)
__global__ void fill_kernel(const int* __restrict__ ei0, const int* __restrict__ ei1,
                            int* __restrict__ cur0, int* __restrict__ cur1,
                            int2* __restrict__ csr0, int2* __restrict__ csr1) {
    const int* ei = blockIdx.y ? ei1 : ei0;
    int* cursor   = blockIdx.y ? cur1 : cur0;
    int2* csr     = blockIdx.y ? csr1 : csr0;
    int chunk = blockIdx.x >> 3;
    int cls   = blockIdx.x & 7;
    int e0 = chunk * FCHUNK;
    int e1 = e0 + FCHUNK; if (e1 > N_EDGES) e1 = N_EDGES;
    int lo = cls * NPC, hi = lo + NPC;
    for (int e = e0 + threadIdx.x; e < e1; e += 256) {
        int dst = __builtin_nontemporal_load(&ei[N_EDGES + e]);
        if (dst >= lo && dst < hi) {
            int src = __builtin_nontemporal_load(&ei[e]);
            int pos = atomicAdd(&cursor[dst], 1);
            csr[pos] = make_int2(src, e);
        }
    }
}

// ------------------------------------------------- edge-attr aggregation (bf16 out)
__global__ void gather_e_kernel(const float* __restrict__ ea0, const float* __restrict__ ea1,
                                const int* __restrict__ rp0, const int* __restrict__ rp1,
                                const int2* __restrict__ csr0, const int2* __restrict__ csr1,
                                unsigned short* __restrict__ agg0,
                                unsigned short* __restrict__ agg1) {
    const float* ea        = blockIdx.y ? ea1 : ea0;
    const int* row_ptr     = blockIdx.y ? rp1 : rp0;
    const int2* csr        = blockIdx.y ? csr1 : csr0;
    unsigned short* agg    = blockIdx.y ? agg1 : agg0;
    int node = blockIdx.x * 32 + (threadIdx.x >> 3);
    if (node >= N_NODES) return;
    int lane = threadIdx.x & 7;
    int start = row_ptr[node], end = row_ptr[node + 1];
    float acc = 0.f;
    int e = start;
    for (; e + 2 <= end; e += 2) {
        int e0 = csr[e].y, e1 = csr[e + 1].y;
        acc += ea[(size_t)e0 * FE + lane] + ea[(size_t)e1 * FE + lane];
    }
    if (e < end) acc += ea[(size_t)csr[e].y * FE + lane];
    agg[(size_t)node * FIN + FX + lane] = f2bf(acc);
}

// ---------------------------------------------------------------- fp32 -> bf16 convert
__global__ void f2bf_kernel(const float* __restrict__ in0, const float* __restrict__ in1,
                            unsigned short* __restrict__ o0, unsigned short* __restrict__ o1) {
    const float* in          = blockIdx.y ? in1 : in0;
    unsigned short* out16    = blockIdx.y ? o1 : o0;
    int i = blockIdx.x * 256 + threadIdx.x;          // over N_NODES*FX/4
    if (i >= N_NODES * FX / 4) return;
    float4 v = reinterpret_cast<const float4*>(in)[i];
    ushort4 o;
    o.x = f2bf(v.x); o.y = f2bf(v.y); o.z = f2bf(v.z); o.w = f2bf(v.w);
    reinterpret_cast<ushort4*>(out16)[i] = o;
}

// --------------------------------------------- weight convert: fp32 -> bf16, K-pad to 160
__global__ void wcvt_kernel(const float* __restrict__ WA, const float* __restrict__ WB,
                            const float* __restrict__ fcW,
                            unsigned short* __restrict__ w16A, unsigned short* __restrict__ w16B,
                            unsigned short* __restrict__ w16fc) {
    const int CONV = 3 * FX * 160;                   // 61440 per branch
    int idx = blockIdx.x * 256 + threadIdx.x;
    if (idx < 2 * CONV) {
        int br = idx / CONV, r = idx % CONV;
        int l = r / (FX * 160), rem = r % (FX * 160);
        int row = rem / 160, k = rem % 160;
        const float* Wsrc = br ? WB : WA;
        float v = (k < FIN) ? Wsrc[((size_t)l * FX + row) * FIN + k] : 0.f;
        (br ? w16B : w16A)[r] = f2bf(v);
    } else {
        int i = idx - 2 * CONV;
        if (i < FX * FX) w16fc[i] = f2bf(fcW[i]);
    }
}

// ------------------------------------------------- sparse gather: agg_x[dst] = sum x[src]
// 16 lanes per node, 16B (8 bf16) per lane per row; fp32 accumulation; bf16 out.
__global__ void gather_kernel(const unsigned short* __restrict__ x0,
                              const unsigned short* __restrict__ x1,
                              const int* __restrict__ rp0, const int* __restrict__ rp1,
                              const int2* __restrict__ csr0, const int2* __restrict__ csr1,
                              unsigned short* __restrict__ agg0,
                              unsigned short* __restrict__ agg1) {
    const unsigned short* x16 = blockIdx.y ? x1 : x0;
    const int* row_ptr        = blockIdx.y ? rp1 : rp0;
    const int2* csr           = blockIdx.y ? csr1 : csr0;
    unsigned short* agg       = blockIdx.y ? agg1 : agg0;
    int node = blockIdx.x * 16 + (threadIdx.x >> 4);
    if (node >= N_NODES) return;
    int lane = threadIdx.x & 15;
    int start = row_ptr[node], end = row_ptr[node + 1];
    const uint4* xr = reinterpret_cast<const uint4*>(x16);   // 16 uint4 per row
    float a[8] = {};
    int e = start;
    for (; e + 4 <= end; e += 4) {
        uint4 v0 = xr[(size_t)csr[e].x     * 16 + lane];
        uint4 v1 = xr[(size_t)csr[e + 1].x * 16 + lane];
        uint4 v2 = xr[(size_t)csr[e + 2].x * 16 + lane];
        uint4 v3 = xr[(size_t)csr[e + 3].x * 16 + lane];
#pragma unroll
        for (int q = 0; q < 4; ++q) {
            unsigned u0 = (&v0.x)[q], u1 = (&v1.x)[q], u2 = (&v2.x)[q], u3 = (&v3.x)[q];
            a[q * 2]     += __uint_as_float(u0 << 16) + __uint_as_float(u1 << 16)
                          + __uint_as_float(u2 << 16) + __uint_as_float(u3 << 16);
            a[q * 2 + 1] += __uint_as_float(u0 & 0xffff0000u) + __uint_as_float(u1 & 0xffff0000u)
                          + __uint_as_float(u2 & 0xffff0000u) + __uint_as_float(u3 & 0xffff0000u);
        }
    }
    for (; e < end; ++e) {
        uint4 v = xr[(size_t)csr[e].x * 16 + lane];
#pragma unroll
        for (int q = 0; q < 4; ++q) {
            unsigned u = (&v.x)[q];
            a[q * 2]     += __uint_as_float(u << 16);
            a[q * 2 + 1] += __uint_as_float(u & 0xffff0000u);
        }
    }
    union { unsigned short us[8]; uint4 v; } o;
#pragma unroll
    for (int q = 0; q < 8; ++q) o.us[q] = f2bf(a[q]);
    *reinterpret_cast<uint4*>(&agg[(size_t)node * FIN + lane * 8]) = o.v;
}

// ------------------------------------------------- MFMA GEMM: out[N,128] = A[N,K]@W16^T + b
// 256 threads = 4 waves; tile M=64 (16 rows/wave), N=128 (8 col-frags), bf16 A staged in LDS.
// Fragment maps (verified m89): A row=l&15, k=(l>>4)*8+j; B col=l&15, same k;
//                               C col=l&15, row=(l>>4)*4+reg.
template <int K, int KSTEPS, int KP, bool LEAKY, bool OUT_BF16>
__global__ void mfma_gemm_kernel(const unsigned short* __restrict__ A0,
                                 const unsigned short* __restrict__ A1,
                                 const unsigned short* __restrict__ W0,
                                 const unsigned short* __restrict__ W1,
                                 const float* __restrict__ b0, const float* __restrict__ b1,
                                 void* __restrict__ O0, void* __restrict__ O1) {
    const unsigned short* A   = blockIdx.y ? A1 : A0;
    const unsigned short* W16 = blockIdx.y ? W1 : W0;
    const float* bias         = blockIdx.y ? b1 : b0;
    void* O                   = blockIdx.y ? O1 : O0;

    constexpr int CH = K / 8;                  // 16B chunks per A row
    constexpr int KLDS = KSTEPS * 32;
    constexpr int PADCH = KLDS / 8 - CH;
    __shared__ unsigned short As[64 * KP];

    const int row0 = blockIdx.x * 64;
    for (int idx = threadIdx.x; idx < 64 * CH; idx += 256) {
        int r = idx / CH, c = idx - r * CH;
        *reinterpret_cast<uint4*>(&As[r * KP + c * 8]) =
            *reinterpret_cast<const uint4*>(&A[(size_t)(row0 + r) * K + c * 8]);
    }
    if constexpr (PADCH > 0) {
        const uint4 z = {0u, 0u, 0u, 0u};
        for (int idx = threadIdx.x; idx < 64 * PADCH; idx += 256) {
            int r = idx / PADCH, c = CH + (idx - r * PADCH);
            *reinterpret_cast<uint4*>(&As[r * KP + c * 8]) = z;
        }
    }
    __syncthreads();

    const int wid = threadIdx.x >> 6;
    const int l   = threadIdx.x & 63;
    const int l16 = l & 15, lhi = l >> 4;
    const unsigned short* Arow = &As[(wid * 16 + l16) * KP + lhi * 8];

    float4v acc[8];
#pragma unroll
    for (int f = 0; f < 8; ++f) acc[f] = (float4v){0.f, 0.f, 0.f, 0.f};

#pragma unroll
    for (int ks = 0; ks < KSTEPS; ++ks) {
        short8v a = *reinterpret_cast<const short8v*>(Arow + ks * 32);
#pragma unroll
        for (int f = 0; f < 8; ++f) {
            short8v b = *reinterpret_cast<const short8v*>(
                &W16[(size_t)(f * 16 + l16) * KLDS + ks * 32 + lhi * 8]);
            acc[f] = __builtin_amdgcn_mfma_f32_16x16x32_bf16(a, b, acc[f], 0, 0, 0);
        }
    }

    float bs[8];
#pragma unroll
    for (int f = 0; f < 8; ++f) bs[f] = bias[f * 16 + l16];

#pragma unroll
    for (int f = 0; f < 8; ++f) {
#pragma unroll
        for (int j = 0; j < 4; ++j) {
            int r = row0 + wid * 16 + lhi * 4 + j;
            if (r < N_NODES) {
                float v = acc[f][j] + bs[f];
                if (LEAKY) v = v > 0.f ? v : 0.01f * v;
                if constexpr (OUT_BF16)
                    ((unsigned short*)O)[(size_t)r * FX + f * 16 + l16] = f2bf(v);
                else
                    ((float*)O)[(size_t)r * FX + f * 16 + l16] = v;
            }
        }
    }
}

// ---------------------------------------------------------------- launch
extern "C" void kernel_launch(void* const* d_in, const int* in_sizes, int n_in,
                              void* d_out, int out_size, void* d_ws, size_t ws_size,
                              hipStream_t stream) {
    const float* x1  = (const float*)d_in[0];
    const int*   ei1 = (const int*)  d_in[1];
    const float* ea1 = (const float*)d_in[2];
    const float* x2  = (const float*)d_in[3];
    const int*   ei2 = (const int*)  d_in[4];
    const float* ea2 = (const float*)d_in[5];
    const float* WA  = (const float*)d_in[6];
    const float* bA  = (const float*)d_in[7];
    const float* WB  = (const float*)d_in[8];
    const float* bB  = (const float*)d_in[9];
    const float* fcW = (const float*)d_in[10];
    const float* fcb = (const float*)d_in[11];
    float* out = (float*)d_out;

    // workspace layout
    unsigned short* agg16a = (unsigned short*)d_ws;          // NPAD*FIN bf16
    unsigned short* agg16b = agg16a + (size_t)NPAD * FIN;
    unsigned short* h16a   = agg16b + (size_t)NPAD * FIN;    // NPAD*FX bf16
    unsigned short* h16b   = h16a + (size_t)NPAD * FX;
    unsigned short* w16A   = h16b + (size_t)NPAD * FX;       // 3*128*160
    unsigned short* w16B   = w16A + 3 * FX * 160;
    unsigned short* w16fc  = w16B + 3 * FX * 160;            // 128*128
    int2* csr0 = (int2*)(((size_t)(w16fc + FX * FX) + 15) & ~(size_t)15);
    int2* csr1 = csr0 + N_EDGES;
    int* deg0    = (int*)(csr1 + N_EDGES);                   // deg0,deg1 contiguous (one memset)
    int* deg1    = deg0 + N_NODES;
    int* rowp0   = deg1 + N_NODES;
    int* rowp1   = rowp0 + N_NODES + 1;
    int* cur0    = rowp1 + N_NODES + 1;
    int* cur1    = cur0 + N_NODES;
    int* part0   = cur1 + N_NODES;
    int* part1   = part0 + NB_SCAN;
    int* base0   = part1 + NB_SCAN;
    int* base1   = base0 + NB_SCAN;
    size_t needed = (size_t)(base1 + NB_SCAN) - (size_t)d_ws;
    if (ws_size < needed) return;                            // output stays poisoned

    const dim3 b256(256);
    const dim3 gE(6250, 2);                       // edges / 256
    const dim3 gS(NB_SCAN, 2);
    const dim3 g1(1, 2);
    const dim3 gF(NCHUNK * NXCD, 2);              // 6256
    const dim3 gGE(1563, 2);
    const dim3 gG(3125, 2);
    const dim3 gC(6250, 2);
    const dim3 gM(782, 2);
    const dim3 gW(544);

    // CSR build, both branches per launch
    hipMemsetAsync(deg0, 0, 2 * N_NODES * sizeof(int), stream);
    hist_kernel<<<gE, b256, 0, stream>>>(ei1, ei2, deg0, deg1);
    scan1_kernel<<<gS, b256, 0, stream>>>(deg0, deg1, part0, part1);
    scan2_kernel<<<g1, b256, 0, stream>>>(part0, part1, base0, base1, rowp0, rowp1);
    scan3_kernel<<<gS, b256, 0, stream>>>(deg0, deg1, base0, base1, rowp0, rowp1, cur0, cur1);
    fill_kernel<<<gF, b256, 0, stream>>>(ei1, ei2, cur0, cur1, csr0, csr1);

    // layer-invariant pieces
    gather_e_kernel<<<gGE, b256, 0, stream>>>(ea1, ea2, rowp0, rowp1, csr0, csr1, agg16a, agg16b);
    f2bf_kernel<<<gC, b256, 0, stream>>>(x1, x2, h16a, h16b);
    wcvt_kernel<<<gW, b256, 0, stream>>>(WA, WB, fcW, w16A, w16B, w16fc);

    // 3 conv layers: gather (bf16 in/out) + MFMA GEMM (bf16 A/W, bf16 out)
    for (int l = 0; l < 3; ++l) {
        gather_kernel<<<gG, b256, 0, stream>>>(h16a, h16b, rowp0, rowp1, csr0, csr1,
                                               agg16a, agg16b);
        mfma_gemm_kernel<FIN, 5, 168, true, true><<<gM, b256, 0, stream>>>(
            agg16a, agg16b, w16A + (size_t)l * FX * 160, w16B + (size_t)l * FX * 160,
            bA + (size_t)l * FX, bB + (size_t)l * FX, h16a, h16b);
    }
    // final fc: bf16 A/W, fp32 out, no activation
    mfma_gemm_kernel<FX, 4, 136, false, false><<<gM, b256, 0, stream>>>(
        h16a, h16b, w16fc, w16fc, fcb, fcb, out, out + (size_t)N_NODES * FX);
}